// Round 4
// baseline (407.047 us; speedup 1.0000x reference)
//
#include <hip/hip_runtime.h>
#include <hip/hip_bf16.h>

// Problem constants
#define B_SZ 8192
#define D_SZ 512
#define K_SZ 4096
#define L_SZ 16
#define M_ALL (B_SZ + K_SZ)   // 12288 rows: targets stacked over codebook

typedef __attribute__((ext_vector_type(8))) short short8v;      // 8 bf16
typedef __attribute__((ext_vector_type(4))) float f32x4;
typedef _Float16 half8v __attribute__((ext_vector_type(8)));    // 8 fp16 = 16B

// ---------------------------------------------------------------------------
// Kernel 1: cast targets+codebook (fp32) into one stacked bf16 matrix [12288 x 512]
// ---------------------------------------------------------------------------
__global__ void cast_bf16_kernel(const float* __restrict__ targets,
                                 const float* __restrict__ codebook,
                                 __hip_bfloat16* __restrict__ abf) {
    int idx = blockIdx.x * blockDim.x + threadIdx.x;
    const int total4 = (M_ALL * D_SZ) / 4;
    if (idx >= total4) return;
    int base = idx * 4;
    const float* src = (base < B_SZ * D_SZ) ? (targets + base)
                                            : (codebook + (base - B_SZ * D_SZ));
    float4 v = *(const float4*)src;
    abf[base + 0] = __float2bfloat16(v.x);
    abf[base + 1] = __float2bfloat16(v.y);
    abf[base + 2] = __float2bfloat16(v.z);
    abf[base + 3] = __float2bfloat16(v.w);
}

// ---------------------------------------------------------------------------
// Kernel 1b: exact fp64 codebook row norms^2 (for algebraic ||r||^2 update)
// ---------------------------------------------------------------------------
__global__ void cn2_kernel(const float* __restrict__ codebook,
                           double* __restrict__ cn2) {
    int row  = blockIdx.x * 4 + (threadIdx.x >> 6);
    int lane = threadIdx.x & 63;
    const float* r = codebook + (size_t)row * D_SZ;
    double s = 0.0;
#pragma unroll
    for (int j = 0; j < 8; j++) { double v = (double)r[lane + 64 * j]; s += v * v; }
#pragma unroll
    for (int o = 32; o > 0; o >>= 1) s += __shfl_down(s, o, 64);
    if (lane == 0) cn2[row] = s;
}

// ---------------------------------------------------------------------------
// Kernel 2: S = A * B^T -> fp16 [M x 4096]. 128x128 tile, 4 waves, 16x16x32 MFMA.
// ---------------------------------------------------------------------------
#define BM 128
#define BN 128
#define BK 32
#define LDSS 40

__global__ __launch_bounds__(256, 2)
void gemm_bt_kernel(const __hip_bfloat16* __restrict__ A,
                    const __hip_bfloat16* __restrict__ Bm,
                    _Float16* __restrict__ C) {
    __shared__ short As[BM * LDSS];
    __shared__ short Bs[BN * LDSS];
    const int tid  = threadIdx.x;
    const int bm   = blockIdx.y * BM;
    const int bn   = blockIdx.x * BN;
    const int wave = tid >> 6, lane = tid & 63;
    const int wm = (wave & 1) * 64, wn = (wave >> 1) * 64;
    const int row16 = lane & 15, quad = lane >> 4;
    const int koff = quad * 8;

    f32x4 acc[4][4] = {};

    const int srow = tid >> 1;
    const int scol = (tid & 1) * 16;
    const short* Ag = (const short*)A;
    const short* Bg = (const short*)Bm;

    for (int k0 = 0; k0 < D_SZ; k0 += BK) {
        short8v a0 = *(const short8v*)(Ag + (size_t)(bm + srow) * D_SZ + k0 + scol);
        short8v a1 = *(const short8v*)(Ag + (size_t)(bm + srow) * D_SZ + k0 + scol + 8);
        short8v b0 = *(const short8v*)(Bg + (size_t)(bn + srow) * D_SZ + k0 + scol);
        short8v b1 = *(const short8v*)(Bg + (size_t)(bn + srow) * D_SZ + k0 + scol + 8);
        __syncthreads();
        *(short8v*)(As + srow * LDSS + scol)     = a0;
        *(short8v*)(As + srow * LDSS + scol + 8) = a1;
        *(short8v*)(Bs + srow * LDSS + scol)     = b0;
        *(short8v*)(Bs + srow * LDSS + scol + 8) = b1;
        __syncthreads();

        short8v af[4], bf[4];
#pragma unroll
        for (int i = 0; i < 4; i++)
            af[i] = *(const short8v*)(As + (wm + i * 16 + row16) * LDSS + koff);
#pragma unroll
        for (int j = 0; j < 4; j++)
            bf[j] = *(const short8v*)(Bs + (wn + j * 16 + row16) * LDSS + koff);
#pragma unroll
        for (int i = 0; i < 4; i++)
#pragma unroll
            for (int j = 0; j < 4; j++)
                acc[i][j] = __builtin_amdgcn_mfma_f32_16x16x32_bf16(af[i], bf[j], acc[i][j], 0, 0, 0);
    }

#pragma unroll
    for (int i = 0; i < 4; i++) {
        int grow = bm + wm + i * 16 + quad * 4;
#pragma unroll
        for (int j = 0; j < 4; j++) {
            int gcol = bn + wn + j * 16 + row16;
#pragma unroll
            for (int r = 0; r < 4; r++)
                C[(size_t)(grow + r) * K_SZ + gcol] = (_Float16)acc[i][j][r];
        }
    }
}

// ---------------------------------------------------------------------------
// Kernel 3: pursuit, wave-per-row. Lane owns g[64] fp32 regs (k = jb*512 +
// lane*8 + e) and rres[8] fp64 regs (i = lane*8 + e). launch_bounds(256,2)
// so the 64-reg g array stays IN REGISTERS (R3's (256,4) caused scratch
// spill: VGPR_Count=64 < live set ~110 -> ~4GB hidden scratch traffic).
// ---------------------------------------------------------------------------
#define MAXC 32
#define MARGIN 1.0f

__global__ __launch_bounds__(256, 2)
void pursuit_kernel(const float* __restrict__ targets,
                    const float* __restrict__ codebook,
                    const _Float16* __restrict__ S,   // [12288 x 4096]; rows >=8192 are Gram
                    const double* __restrict__ cn2,   // [4096] exact ||c_k||^2
                    float* __restrict__ out) {
    const int wave = threadIdx.x >> 6;
    const int lane = threadIdx.x & 63;
    const int b = blockIdx.x * 4 + wave;
    const int lane8 = lane * 8;

    __shared__ int s_cnt[4];
    __shared__ int s_cand[4][MAXC];
    int* cnt  = &s_cnt[wave];
    int* cand = s_cand[wave];

    // ---- g regs from fp16 score row ----
    float g_r[64];
    {
        const _Float16* g0 = S + (size_t)b * K_SZ + lane8;
#pragma unroll
        for (int jb = 0; jb < 8; jb++) {
            half8v h = *(const half8v*)(g0 + jb * 512);
#pragma unroll
            for (int e = 0; e < 8; e++) g_r[jb * 8 + e] = (float)h[e];
        }
    }

    // ---- lane-private fp64 residual + tn2 ----
    double rres[8];
    double loc = 0.0;
    {
        const float* tg = targets + (size_t)b * D_SZ + lane8;
        float4 t0 = *(const float4*)tg;
        float4 t1 = *(const float4*)(tg + 4);
        rres[0] = t0.x; rres[1] = t0.y; rres[2] = t0.z; rres[3] = t0.w;
        rres[4] = t1.x; rres[5] = t1.y; rres[6] = t1.z; rres[7] = t1.w;
#pragma unroll
        for (int e = 0; e < 8; e++) loc += rres[e] * rres[e];
    }
#pragma unroll
    for (int o = 32; o > 0; o >>= 1) loc += __shfl_xor(loc, o, 64);
    const double tn2 = loc;
    double rn2 = tn2;
    const bool tgt_ok = (sqrt(tn2) >= 1e-8);

    float* out_seq  = out;
    float* out_mask = out + (size_t)B_SZ * L_SZ;
    float* out_res  = out + (size_t)2 * B_SZ * L_SZ;

    double decay = 1.0;
    for (int t = 0; t < L_SZ; t++) {
        decay *= 0.95;
        bool active = (sqrt(rn2) >= 0.01) && tgt_ok;   // wave-uniform
        if (!active) {
            if (lane == 0) {
                out_seq[(size_t)b * L_SZ + t]  = 0.0f;
                out_mask[(size_t)b * L_SZ + t] = 0.0f;
            }
            continue;
        }

        // ---- approx max |g|: balanced tree (dep depth 6, not 64) ----
        float t32[32];
#pragma unroll
        for (int j = 0; j < 32; j++) t32[j] = fmaxf(fabsf(g_r[j]), fabsf(g_r[j + 32]));
#pragma unroll
        for (int j = 0; j < 16; j++) t32[j] = fmaxf(t32[j], t32[j + 16]);
#pragma unroll
        for (int j = 0; j < 8; j++)  t32[j] = fmaxf(t32[j], t32[j + 8]);
#pragma unroll
        for (int j = 0; j < 4; j++)  t32[j] = fmaxf(t32[j], t32[j + 4]);
        float m = fmaxf(fmaxf(t32[0], t32[1]), fmaxf(t32[2], t32[3]));
        float M = m;
#pragma unroll
        for (int o = 32; o > 0; o >>= 1) M = fmaxf(M, __shfl_xor(M, o, 64));
        float thr = M - MARGIN;

        // ---- candidate collection (per-wave LDS list) ----
        if (lane == 0) *cnt = 0;
        if (m >= thr) {
#pragma unroll
            for (int jb = 0; jb < 8; jb++)
#pragma unroll
                for (int e = 0; e < 8; e++)
                    if (fabsf(g_r[jb * 8 + e]) >= thr) {
                        int p = atomicAdd(cnt, 1);
                        if (p < MAXC) cand[p] = jb * 512 + lane8 + e;
                    }
        }
        __threadfence_block();
        int nc = min(*cnt, MAXC);

        // ---- exact fp64 rescore. Fast path nc<=2: both rows pre-issued,
        //      winner's row kept in regs for the residual update. ----
        int bk; double bv;
        float4 w0, w1;                       // winner codebook row (lane slice)
        if (nc <= 2) {
            int kA = cand[0];
            int kB = cand[nc - 1];           // == kA when nc==1
            const float* ca = codebook + (size_t)kA * D_SZ + lane8;
            const float* cb = codebook + (size_t)kB * D_SZ + lane8;
            float4 a0 = *(const float4*)ca;  // all four loads issued together
            float4 a1 = *(const float4*)(ca + 4);
            float4 b0 = *(const float4*)cb;
            float4 b1 = *(const float4*)(cb + 4);
            double sA = rres[0] * (double)a0.x + rres[1] * (double)a0.y
                      + rres[2] * (double)a0.z + rres[3] * (double)a0.w
                      + rres[4] * (double)a1.x + rres[5] * (double)a1.y
                      + rres[6] * (double)a1.z + rres[7] * (double)a1.w;
            double sB = rres[0] * (double)b0.x + rres[1] * (double)b0.y
                      + rres[2] * (double)b0.z + rres[3] * (double)b0.w
                      + rres[4] * (double)b1.x + rres[5] * (double)b1.y
                      + rres[6] * (double)b1.z + rres[7] * (double)b1.w;
#pragma unroll
            for (int o = 32; o > 0; o >>= 1) {
                sA += __shfl_xor(sA, o, 64);
                sB += __shfl_xor(sB, o, 64);
            }
            bool Bwins = (nc == 2) &&
                         (fabs(sB) > fabs(sA) || (fabs(sB) == fabs(sA) && kB < kA));
            if (Bwins) { bk = kB; bv = sB; w0 = b0; w1 = b1; }
            else       { bk = kA; bv = sA; w0 = a0; w1 = a1; }
        } else {
            bk = -1; bv = 0.0; bool have = false;
            for (int ci = 0; ci < nc; ci++) {
                int k = cand[ci];
                const float* crow = codebook + (size_t)k * D_SZ + lane8;
                float4 c0 = *(const float4*)crow;
                float4 c1 = *(const float4*)(crow + 4);
                double s = rres[0] * (double)c0.x + rres[1] * (double)c0.y
                         + rres[2] * (double)c0.z + rres[3] * (double)c0.w
                         + rres[4] * (double)c1.x + rres[5] * (double)c1.y
                         + rres[6] * (double)c1.z + rres[7] * (double)c1.w;
#pragma unroll
                for (int o = 32; o > 0; o >>= 1) s += __shfl_xor(s, o, 64);
                if (!have || fabs(s) > fabs(bv) ||
                    (fabs(s) == fabs(bv) && k < bk)) { bk = k; bv = s; have = true; }
            }
            const float* crow = codebook + (size_t)bk * D_SZ + lane8;   // rare reload
            w0 = *(const float4*)crow;
            w1 = *(const float4*)(crow + 4);
        }

        // ---- decision + algebraic exact ||r||^2 update (wave-uniform) ----
        double sd = ((bv >= 0.0) ? 1.0 : -1.0) * decay;
        rn2 = rn2 - 2.0 * sd * bv + sd * sd * cn2[bk];
        if (lane == 0) {
            out_seq[(size_t)b * L_SZ + t]  = (float)((bv >= 0.0) ? bk : (-bk - 1));
            out_mask[(size_t)b * L_SZ + t] = 1.0f;
        }
        const float sdf = (float)sd;

        // ---- approx score update with fp16 Gram row ----
        const _Float16* Grow = S + (size_t)(B_SZ + bk) * K_SZ + lane8;
#pragma unroll
        for (int jb = 0; jb < 8; jb++) {
            half8v h = *(const half8v*)(Grow + jb * 512);
#pragma unroll
            for (int e = 0; e < 8; e++) g_r[jb * 8 + e] -= sdf * (float)h[e];
        }
        // ---- exact lane-private residual update (winner row already in regs) ----
        rres[0] -= sd * (double)w0.x; rres[1] -= sd * (double)w0.y;
        rres[2] -= sd * (double)w0.z; rres[3] -= sd * (double)w0.w;
        rres[4] -= sd * (double)w1.x; rres[5] -= sd * (double)w1.y;
        rres[6] -= sd * (double)w1.z; rres[7] -= sd * (double)w1.w;
    }

    // ---- final residual ----
    {
        float* o = out_res + (size_t)b * D_SZ + lane8;
        float4 r0, r1;
        r0.x = (float)rres[0]; r0.y = (float)rres[1]; r0.z = (float)rres[2]; r0.w = (float)rres[3];
        r1.x = (float)rres[4]; r1.y = (float)rres[5]; r1.z = (float)rres[6]; r1.w = (float)rres[7];
        *(float4*)o = r0;
        *(float4*)(o + 4) = r1;
    }
}

// ---------------------------------------------------------------------------
extern "C" void kernel_launch(void* const* d_in, const int* in_sizes, int n_in,
                              void* d_out, int out_size, void* d_ws, size_t ws_size,
                              hipStream_t stream) {
    const float* targets  = (const float*)d_in[0];
    const float* codebook = (const float*)d_in[1];
    float* out = (float*)d_out;

    __hip_bfloat16* abf = (__hip_bfloat16*)d_ws;                         // 12,582,912 B
    _Float16* S = (_Float16*)((char*)d_ws + (size_t)M_ALL * D_SZ * 2);   // 100,663,296 B
    double* cn2 = (double*)((char*)d_ws + (size_t)M_ALL * D_SZ * 2
                                        + (size_t)M_ALL * K_SZ * 2);     // 32,768 B
    // total ws needed: ~113.3 MB

    int total4 = (M_ALL * D_SZ) / 4;
    cast_bf16_kernel<<<(total4 + 255) / 256, 256, 0, stream>>>(targets, codebook, abf);
    cn2_kernel<<<K_SZ / 4, 256, 0, stream>>>(codebook, cn2);

    dim3 ggrid(K_SZ / BN, M_ALL / BM);
    gemm_bt_kernel<<<ggrid, 256, 0, stream>>>(abf, abf + (size_t)B_SZ * D_SZ, S);

    pursuit_kernel<<<B_SZ / 4, 256, 0, stream>>>(targets, codebook, S, cn2, out);
}